// Round 1
// baseline (189.013 us; speedup 1.0000x reference)
//
#include <hip/hip_runtime.h>

#define NTHR 256
#define NROWB 256           // rows per block (1 row / thread)
constexpr int NBR = 29;
constexpr float EPS = 1e-5f;
constexpr int NBLOCKS = 1048576 / NROWB; // 4096

__global__ __launch_bounds__(NTHR) void recovery_net_kernel(
    const float* __restrict__ xcon, const int* __restrict__ xcat,
    const float* __restrict__ embt, const float* __restrict__ w1,
    const float* __restrict__ b1,   const float* __restrict__ w2,
    const float* __restrict__ b2,
    const float* __restrict__ cbn_g, const float* __restrict__ cbn_b,
    const float* __restrict__ cbn_m, const float* __restrict__ cbn_v,
    const float* __restrict__ f1w, const float* __restrict__ f1b,
    const float* __restrict__ f2w, const float* __restrict__ f2b,
    const float* __restrict__ f3w, const float* __restrict__ f3b,
    const float* __restrict__ f4w, const float* __restrict__ f4b,
    const float* __restrict__ bn1g, const float* __restrict__ bn1b,
    const float* __restrict__ bn1m, const float* __restrict__ bn1v,
    const float* __restrict__ bn2g, const float* __restrict__ bn2b,
    const float* __restrict__ bn2m, const float* __restrict__ bn2v,
    const float* __restrict__ bn3g, const float* __restrict__ bn3b,
    const float* __restrict__ bn3m, const float* __restrict__ bn3v,
    float2* __restrict__ out)
{
    // ---- LDS: folded weights + staged inputs ----
    __shared__ float s_emb[NBR * 5 * 8];   // emb rows padded to 8 floats
    __shared__ float s_w1 [NBR * 6 * 8];   // w1[j][d][e] rows padded to 8
    __shared__ float s_b1 [NBR * 8];
    __shared__ float s_w2 [NBR * 8];
    __shared__ float s_b2 [NBR];
    __shared__ float s_f1w[36 * 36];
    __shared__ float s_f1b[36];
    __shared__ float s_f2w[18 * 36];
    __shared__ float s_f2b[18];
    __shared__ float s_f3w[9 * 20];        // rows padded 18 -> 20
    __shared__ float s_f3b[9];
    __shared__ float s_f4w[2 * 12];        // rows padded 9 -> 12
    __shared__ float s_f4b[2];
    __shared__ float s_cs[7], s_ct[7];
    __shared__ unsigned int s_catp[NROWB * NBR / 4]; // packed byte categories
    __shared__ float s_xcon[NROWB * 7];

    const int t = threadIdx.x;

    // ---- fold BN into weights, stage to LDS ----
    for (int i = t; i < NBR * 5 * 6; i += NTHR) {
        int j = i / 30, rm = i % 30;
        s_emb[(j * 5 + rm / 6) * 8 + rm % 6] = embt[i];
    }
    for (int i = t; i < NBR * 36; i += NTHR) {
        int j = i / 36, rm = i % 36;
        s_w1[(j * 6 + rm / 6) * 8 + rm % 6] = w1[i];
    }
    for (int i = t; i < NBR * 6; i += NTHR) {
        s_b1[(i / 6) * 8 + i % 6] = b1[i];
        s_w2[(i / 6) * 8 + i % 6] = w2[i];
    }
    if (t < NBR) s_b2[t] = b2[t];
    if (t < 7) {
        float s = cbn_g[t] * rsqrtf(cbn_v[t] + EPS);
        s_cs[t] = s;
        s_ct[t] = cbn_b[t] - cbn_m[t] * s;
    }
    for (int i = t; i < 36 * 36; i += NTHR) {
        int o = i / 36;
        float s = bn1g[o] * rsqrtf(bn1v[o] + EPS);
        s_f1w[i] = f1w[i] * s;
    }
    if (t < 36) {
        float s = bn1g[t] * rsqrtf(bn1v[t] + EPS);
        s_f1b[t] = f1b[t] * s + bn1b[t] - bn1m[t] * s;
    }
    for (int i = t; i < 18 * 36; i += NTHR) {
        int o = i / 36;
        float s = bn2g[o] * rsqrtf(bn2v[o] + EPS);
        s_f2w[i] = f2w[i] * s;
    }
    if (t < 18) {
        float s = bn2g[t] * rsqrtf(bn2v[t] + EPS);
        s_f2b[t] = f2b[t] * s + bn2b[t] - bn2m[t] * s;
    }
    for (int i = t; i < 9 * 18; i += NTHR) {
        int o = i / 18, c = i % 18;
        float s = bn3g[o] * rsqrtf(bn3v[o] + EPS);
        s_f3w[o * 20 + c] = f3w[i] * s;
    }
    if (t < 9) {
        float s = bn3g[t] * rsqrtf(bn3v[t] + EPS);
        s_f3b[t] = f3b[t] * s + bn3b[t] - bn3m[t] * s;
    }
    if (t < 18) s_f4w[(t / 9) * 12 + t % 9] = f4w[t];
    if (t < 2)  s_f4b[t] = f4b[t];

    // ---- stage this block's input rows (coalesced) ----
    {
        const int4* src = (const int4*)(xcat + (size_t)blockIdx.x * NROWB * NBR);
        for (int i = t; i < NROWB * NBR / 4; i += NTHR) {
            int4 v = src[i];
            s_catp[i] = (unsigned)(v.x & 0xff) | ((unsigned)(v.y & 0xff) << 8) |
                        ((unsigned)(v.z & 0xff) << 16) | ((unsigned)(v.w & 0xff) << 24);
        }
    }
    {
        const float4* src = (const float4*)(xcon + (size_t)blockIdx.x * NROWB * 7);
        float4* dst = (float4*)s_xcon;
        for (int i = t; i < NROWB * 7 / 4; i += NTHR) dst[i] = src[i];
    }
    __syncthreads();

    // ---- per-thread row pipeline ----
    const unsigned char* myc = ((const unsigned char*)s_catp) + t * NBR;

    float xin[36];
#pragma unroll
    for (int k = 0; k < 7; k++)
        xin[k] = s_xcon[t * 7 + k] * s_cs[k] + s_ct[k];

    for (int j = 0; j < NBR; j++) {
        int c = (int)myc[j];
        const float* e = &s_emb[(j * 5 + c) * 8];
        float h[6];
#pragma unroll
        for (int q = 0; q < 6; q++) h[q] = s_b1[j * 8 + q];
#pragma unroll
        for (int d = 0; d < 6; d++) {
            float ed = e[d];
#pragma unroll
            for (int q = 0; q < 6; q++) h[q] += ed * s_w1[(j * 6 + d) * 8 + q];
        }
        float xe = s_b2[j];
#pragma unroll
        for (int q = 0; q < 6; q++) xe += fmaxf(h[q], 0.f) * s_w2[j * 8 + q];
        xin[7 + j] = xe;
    }

    float h1[36];
#pragma unroll
    for (int o = 0; o < 36; o++) {
        float a = s_f1b[o];
#pragma unroll
        for (int i = 0; i < 36; i++) a += xin[i] * s_f1w[o * 36 + i];
        h1[o] = fmaxf(a, 0.f);
    }

    float h2[18];
#pragma unroll
    for (int o = 0; o < 18; o++) {
        float a = s_f2b[o];
#pragma unroll
        for (int i = 0; i < 36; i++) a += h1[i] * s_f2w[o * 36 + i];
        h2[o] = fmaxf(a, 0.f);
    }

    float h3[9];
#pragma unroll
    for (int o = 0; o < 9; o++) {
        float a = s_f3b[o];
#pragma unroll
        for (int i = 0; i < 18; i++) a += h2[i] * s_f3w[o * 20 + i];
        h3[o] = fmaxf(a, 0.f);
    }

    float l0 = s_f4b[0], l1 = s_f4b[1];
#pragma unroll
    for (int i = 0; i < 9; i++) {
        l0 += h3[i] * s_f4w[i];
        l1 += h3[i] * s_f4w[12 + i];
    }

    float m  = fmaxf(l0, l1);
    float e0 = __expf(l0 - m), e1 = __expf(l1 - m);
    float inv = 1.f / (e0 + e1);

    const int r = blockIdx.x * NROWB + t;
    out[r] = make_float2(e0 * inv, e1 * inv);
}

extern "C" void kernel_launch(void* const* d_in, const int* in_sizes, int n_in,
                              void* d_out, int out_size, void* d_ws, size_t ws_size,
                              hipStream_t stream) {
    (void)in_sizes; (void)n_in; (void)d_ws; (void)ws_size; (void)out_size;
    recovery_net_kernel<<<NBLOCKS, NTHR, 0, stream>>>(
        (const float*)d_in[0],  (const int*)d_in[1],
        (const float*)d_in[2],  (const float*)d_in[3],
        (const float*)d_in[4],  (const float*)d_in[5],
        (const float*)d_in[6],
        (const float*)d_in[7],  (const float*)d_in[8],
        (const float*)d_in[9],  (const float*)d_in[10],
        (const float*)d_in[11], (const float*)d_in[12],
        (const float*)d_in[13], (const float*)d_in[14],
        (const float*)d_in[15], (const float*)d_in[16],
        (const float*)d_in[17], (const float*)d_in[18],
        (const float*)d_in[19], (const float*)d_in[20],
        (const float*)d_in[21], (const float*)d_in[22],
        (const float*)d_in[23], (const float*)d_in[24],
        (const float*)d_in[25], (const float*)d_in[26],
        (const float*)d_in[27], (const float*)d_in[28],
        (const float*)d_in[29], (const float*)d_in[30],
        (float2*)d_out);
}

// Round 2
// 97.972 us; speedup vs baseline: 1.9293x; 1.9293x over previous
//
#include <hip/hip_runtime.h>

#define NTHR 256
#define NROWB 256
constexpr int NBR = 29;
constexpr float EPS = 1e-5f;
constexpr int NBLOCKS = 1048576 / NROWB; // 4096

// d_ws float offsets (folded params + embedding-MLP lookup table)
#define W1_OFF 0        // [36][36] fc1 weights, bn1+cbn folded
#define B1_OFF 1296     // [36]
#define W2_OFF 1332     // [18][36] fc2, bn2 folded
#define B2_OFF 1980     // [18]
#define W3_OFF 1998     // [9][18] fc3, bn3 folded
#define B3_OFF 2160     // [9]
#define W4_OFF 2169     // [9]  (fc4 row1 - row0)
#define B4_OFF 2178     // [1]
#define TAB_OFF 2179    // [29][5] embedding-MLP output table
// total 2324 floats = 9296 B

__global__ __launch_bounds__(NTHR) void prep_kernel(
    const float* __restrict__ embt, const float* __restrict__ w1,
    const float* __restrict__ b1,   const float* __restrict__ w2,
    const float* __restrict__ b2,
    const float* __restrict__ cbn_g, const float* __restrict__ cbn_b,
    const float* __restrict__ cbn_m, const float* __restrict__ cbn_v,
    const float* __restrict__ f1w, const float* __restrict__ f1b,
    const float* __restrict__ f2w, const float* __restrict__ f2b,
    const float* __restrict__ f3w, const float* __restrict__ f3b,
    const float* __restrict__ f4w, const float* __restrict__ f4b,
    const float* __restrict__ bn1g, const float* __restrict__ bn1b,
    const float* __restrict__ bn1m, const float* __restrict__ bn1v,
    const float* __restrict__ bn2g, const float* __restrict__ bn2b,
    const float* __restrict__ bn2m, const float* __restrict__ bn2v,
    const float* __restrict__ bn3g, const float* __restrict__ bn3b,
    const float* __restrict__ bn3m, const float* __restrict__ bn3v,
    float* __restrict__ ws)
{
    const int t = threadIdx.x;

    // fc1 weights: fold bn1 scale (rows) and cbn scale (first 7 cols)
    for (int i = t; i < 1296; i += NTHR) {
        int o = i / 36, k = i % 36;
        float s1 = bn1g[o] * rsqrtf(bn1v[o] + EPS);
        float w = f1w[i] * s1;
        if (k < 7) w *= cbn_g[k] * rsqrtf(cbn_v[k] + EPS);
        ws[W1_OFF + i] = w;
    }
    // fc1 bias: bn1 fold + absorb cbn shift of first 7 inputs
    if (t < 36) {
        float s1 = bn1g[t] * rsqrtf(bn1v[t] + EPS);
        float acc = f1b[t] * s1 + bn1b[t] - bn1m[t] * s1;
        for (int k = 0; k < 7; k++) {
            float cs = cbn_g[k] * rsqrtf(cbn_v[k] + EPS);
            float ct = cbn_b[k] - cbn_m[k] * cs;
            acc += f1w[t * 36 + k] * s1 * ct;
        }
        ws[B1_OFF + t] = acc;
    }
    for (int i = t; i < 648; i += NTHR) {
        int o = i / 36;
        float s = bn2g[o] * rsqrtf(bn2v[o] + EPS);
        ws[W2_OFF + i] = f2w[i] * s;
    }
    if (t < 18) {
        float s = bn2g[t] * rsqrtf(bn2v[t] + EPS);
        ws[B2_OFF + t] = f2b[t] * s + bn2b[t] - bn2m[t] * s;
    }
    for (int i = t; i < 162; i += NTHR) {
        int o = i / 18;
        float s = bn3g[o] * rsqrtf(bn3v[o] + EPS);
        ws[W3_OFF + i] = f3w[i] * s;
    }
    if (t < 9) {
        float s = bn3g[t] * rsqrtf(bn3v[t] + EPS);
        ws[B3_OFF + t] = f3b[t] * s + bn3b[t] - bn3m[t] * s;
    }
    if (t < 9)  ws[W4_OFF + t] = f4w[9 + t] - f4w[t];
    if (t == 0) ws[B4_OFF] = f4b[1] - f4b[0];

    // embedding-MLP lookup table: 29 features x 5 categories
    if (t < 145) {
        int j = t / 5, c = t % 5;
        float xe = b2[j];
        for (int e = 0; e < 6; e++) {
            float a = b1[j * 6 + e];
            for (int d = 0; d < 6; d++)
                a += embt[(j * 5 + c) * 6 + d] * w1[j * 36 + d * 6 + e];
            xe += fmaxf(a, 0.f) * w2[j * 6 + e];
        }
        ws[TAB_OFF + t] = xe;
    }
}

__global__ __launch_bounds__(NTHR) void recovery_net_kernel(
    const float* __restrict__ xcon, const int* __restrict__ xcat,
    const float* __restrict__ ws, float2* __restrict__ out)
{
    __shared__ float s_tab[152];                    // [29][5] + pad
    __shared__ unsigned int s_catp[NROWB * NBR / 4]; // packed byte categories
    __shared__ float s_xcon[NROWB * 7];

    const int t = threadIdx.x;

    if (t < 145) s_tab[t] = ws[TAB_OFF + t];
    {
        const int4* src = (const int4*)(xcat + (size_t)blockIdx.x * NROWB * NBR);
        for (int i = t; i < NROWB * NBR / 4; i += NTHR) {
            int4 v = src[i];
            s_catp[i] = (unsigned)(v.x & 0xff) | ((unsigned)(v.y & 0xff) << 8) |
                        ((unsigned)(v.z & 0xff) << 16) | ((unsigned)(v.w & 0xff) << 24);
        }
    }
    {
        const float4* src = (const float4*)(xcon + (size_t)blockIdx.x * NROWB * 7);
        float4* dst = (float4*)s_xcon;
        for (int i = t; i < NROWB * 7 / 4; i += NTHR) dst[i] = src[i];
    }
    __syncthreads();

    const unsigned char* myc = ((const unsigned char*)s_catp) + t * NBR;

    // xin = [raw xcon (cbn folded into fc1), table lookups]
    float xin[36];
#pragma unroll
    for (int k = 0; k < 7; k++) xin[k] = s_xcon[t * 7 + k];
#pragma unroll
    for (int j = 0; j < NBR; j++) xin[7 + j] = s_tab[j * 5 + (int)myc[j]];

    // fc1+bn1+relu — weights via uniform (scalar) loads from ws
    float h1[36];
#pragma unroll
    for (int o = 0; o < 36; o++) {
        float a = ws[B1_OFF + o];
#pragma unroll
        for (int i = 0; i < 36; i++) a += xin[i] * ws[W1_OFF + o * 36 + i];
        h1[o] = fmaxf(a, 0.f);
    }

    float h2[18];
#pragma unroll
    for (int o = 0; o < 18; o++) {
        float a = ws[B2_OFF + o];
#pragma unroll
        for (int i = 0; i < 36; i++) a += h1[i] * ws[W2_OFF + o * 36 + i];
        h2[o] = fmaxf(a, 0.f);
    }

    float h3[9];
#pragma unroll
    for (int o = 0; o < 9; o++) {
        float a = ws[B3_OFF + o];
#pragma unroll
        for (int i = 0; i < 18; i++) a += h2[i] * ws[W3_OFF + o * 18 + i];
        h3[o] = fmaxf(a, 0.f);
    }

    // logit delta d = l1 - l0; softmax == sigmoid(d)
    float d = ws[B4_OFF];
#pragma unroll
    for (int i = 0; i < 9; i++) d += h3[i] * ws[W4_OFF + i];

    float e = __expf(-fabsf(d));
    float r = 1.f / (1.f + e);          // prob of the larger logit
    float p1 = d > 0.f ? r : 1.f - r;   // sigmoid(d)

    const int row = blockIdx.x * NROWB + t;
    out[row] = make_float2(1.f - p1, p1);
}

extern "C" void kernel_launch(void* const* d_in, const int* in_sizes, int n_in,
                              void* d_out, int out_size, void* d_ws, size_t ws_size,
                              hipStream_t stream) {
    (void)in_sizes; (void)n_in; (void)ws_size; (void)out_size;
    float* ws = (float*)d_ws;
    prep_kernel<<<1, NTHR, 0, stream>>>(
        (const float*)d_in[2],  (const float*)d_in[3],
        (const float*)d_in[4],  (const float*)d_in[5],
        (const float*)d_in[6],
        (const float*)d_in[7],  (const float*)d_in[8],
        (const float*)d_in[9],  (const float*)d_in[10],
        (const float*)d_in[11], (const float*)d_in[12],
        (const float*)d_in[13], (const float*)d_in[14],
        (const float*)d_in[15], (const float*)d_in[16],
        (const float*)d_in[17], (const float*)d_in[18],
        (const float*)d_in[19], (const float*)d_in[20],
        (const float*)d_in[21], (const float*)d_in[22],
        (const float*)d_in[23], (const float*)d_in[24],
        (const float*)d_in[25], (const float*)d_in[26],
        (const float*)d_in[27], (const float*)d_in[28],
        (const float*)d_in[29], (const float*)d_in[30],
        ws);
    recovery_net_kernel<<<NBLOCKS, NTHR, 0, stream>>>(
        (const float*)d_in[0], (const int*)d_in[1], ws, (float2*)d_out);
}

// Round 4
// 84.426 us; speedup vs baseline: 2.2388x; 1.1604x over previous
//
#include <hip/hip_runtime.h>

typedef _Float16 f16x8 __attribute__((ext_vector_type(8)));
typedef __fp16 fp16x2 __attribute__((ext_vector_type(2)));
typedef float f32x4 __attribute__((ext_vector_type(4)));

#define NTHR 256
constexpr int NBR = 29;
constexpr float EPS = 1e-5f;
constexpr int NBLOCKS = 4096;   // 1048576 / 256 rows per block

// ---- ws byte offsets (written by prep_kernel every call) ----
#define TAB_B   0       // f32 [29*8]  embedding-MLP table, stride 8
#define W1_B    1024    // f16 [48][64]  fc1 (bn1+cbn folded), n-major, k padded
#define W2_B    7168    // f16 [32][64]  fc2 (bn2 folded)
#define W3_B    11264   // f16 [16][32]  fc3 (bn3 folded)
#define B1_B    12288   // f32 [48]
#define B2_B    12544   // f32 [32]
#define B3_B    12672   // f32 [16]
#define W4_B    12736   // f32 [16]  (fc4 row1-row0, padded)
#define B4_B    12800   // f32 [1]

__device__ __forceinline__ ushort f16bits(float x) {
    union { _Float16 h; ushort u; } c; c.h = (_Float16)x; return c.u;
}

__device__ __forceinline__ uint pk2(float a, float b) {
    union { fp16x2 h; uint u; } c; c.h = __builtin_amdgcn_cvt_pkrtz(a, b); return c.u;
}

// A fragment: row-major LDS [row][64] f16, XOR-swizzled. lane: m=l&15, k-slices 4g.. / 16+4g..
__device__ __forceinline__ f16x8 lda_frag(const char* xb, int row, int kb, int g) {
    int base = row * 128 + kb * 2 + 8 * g;
    int sw = (row & 7) << 4;
    uint2 lo = *(const uint2*)(xb + (base ^ sw));
    uint2 hi = *(const uint2*)(xb + ((base + 32) ^ sw));
    union { uint u[4]; f16x8 v; } f;
    f.u[0] = lo.x; f.u[1] = lo.y; f.u[2] = hi.x; f.u[3] = hi.y;
    return f.v;
}

// B fragment from global f16 weights stored [n][stride]: lane n=l&15 of tile
__device__ __forceinline__ f16x8 ldb_frag(const ushort* wp, int n, int stride, int kb, int g) {
    const ushort* p = wp + n * stride + kb + 4 * g;
    uint2 lo = *(const uint2*)p;
    uint2 hi = *(const uint2*)(p + 16);
    union { uint u[4]; f16x8 v; } f;
    f.u[0] = lo.x; f.u[1] = lo.y; f.u[2] = hi.x; f.u[3] = hi.y;
    return f.v;
}

__global__ __launch_bounds__(NTHR) void prep_kernel(
    const float* __restrict__ embt, const float* __restrict__ w1,
    const float* __restrict__ b1,   const float* __restrict__ w2,
    const float* __restrict__ b2,
    const float* __restrict__ cbn_g, const float* __restrict__ cbn_b,
    const float* __restrict__ cbn_m, const float* __restrict__ cbn_v,
    const float* __restrict__ f1w, const float* __restrict__ f1b,
    const float* __restrict__ f2w, const float* __restrict__ f2b,
    const float* __restrict__ f3w, const float* __restrict__ f3b,
    const float* __restrict__ f4w, const float* __restrict__ f4b,
    const float* __restrict__ bn1g, const float* __restrict__ bn1b,
    const float* __restrict__ bn1m, const float* __restrict__ bn1v,
    const float* __restrict__ bn2g, const float* __restrict__ bn2b,
    const float* __restrict__ bn2m, const float* __restrict__ bn2v,
    const float* __restrict__ bn3g, const float* __restrict__ bn3b,
    const float* __restrict__ bn3m, const float* __restrict__ bn3v,
    char* __restrict__ ws)
{
    const int t = threadIdx.x;
    float* tab = (float*)(ws + TAB_B);
    ushort* w1o = (ushort*)(ws + W1_B);
    ushort* w2o = (ushort*)(ws + W2_B);
    ushort* w3o = (ushort*)(ws + W3_B);
    float* b1o = (float*)(ws + B1_B);
    float* b2o = (float*)(ws + B2_B);
    float* b3o = (float*)(ws + B3_B);
    float* w4o = (float*)(ws + W4_B);
    float* b4o = (float*)(ws + B4_B);

    // embedding-MLP lookup table [29][8] (stride 8, cols 5-7 zero)
    for (int i = t; i < 232; i += NTHR) {
        int j = i / 8, c = i % 8;
        float xe = 0.f;
        if (c < 5) {
            xe = b2[j];
            for (int e = 0; e < 6; e++) {
                float a = b1[j * 6 + e];
                for (int d = 0; d < 6; d++)
                    a += embt[(j * 5 + c) * 6 + d] * w1[j * 36 + d * 6 + e];
                xe += fmaxf(a, 0.f) * w2[j * 6 + e];
            }
        }
        tab[i] = xe;
    }
    // fc1: [48 n][64 k] f16, bn1 scale on rows, cbn scale on cols<7, pads zero
    for (int i = t; i < 3072; i += NTHR) {
        int n = i / 64, k = i % 64;
        float v = 0.f;
        if (n < 36 && k < 36) {
            float s1 = bn1g[n] * rsqrtf(bn1v[n] + EPS);
            v = f1w[n * 36 + k] * s1;
            if (k < 7) v *= cbn_g[k] * rsqrtf(cbn_v[k] + EPS);
        }
        w1o[i] = f16bits(v);
    }
    if (t < 48) {
        float v = 0.f;
        if (t < 36) {
            float s1 = bn1g[t] * rsqrtf(bn1v[t] + EPS);
            v = f1b[t] * s1 + bn1b[t] - bn1m[t] * s1;
            for (int k = 0; k < 7; k++) {
                float cs = cbn_g[k] * rsqrtf(cbn_v[k] + EPS);
                float ct = cbn_b[k] - cbn_m[k] * cs;
                v += f1w[t * 36 + k] * s1 * ct;
            }
        }
        b1o[t] = v;
    }
    // fc2: [32 n][64 k]
    for (int i = t; i < 2048; i += NTHR) {
        int n = i / 64, k = i % 64;
        float v = 0.f;
        if (n < 18 && k < 36) {
            float s = bn2g[n] * rsqrtf(bn2v[n] + EPS);
            v = f2w[n * 36 + k] * s;
        }
        w2o[i] = f16bits(v);
    }
    if (t < 32) {
        float v = 0.f;
        if (t < 18) {
            float s = bn2g[t] * rsqrtf(bn2v[t] + EPS);
            v = f2b[t] * s + bn2b[t] - bn2m[t] * s;
        }
        b2o[t] = v;
    }
    // fc3: [16 n][32 k]
    for (int i = t; i < 512; i += NTHR) {
        int n = i / 32, k = i % 32;
        float v = 0.f;
        if (n < 9 && k < 18) {
            float s = bn3g[n] * rsqrtf(bn3v[n] + EPS);
            v = f3w[n * 18 + k] * s;
        }
        w3o[i] = f16bits(v);
    }
    if (t < 16) {
        float v = 0.f;
        if (t < 9) {
            float s = bn3g[t] * rsqrtf(bn3v[t] + EPS);
            v = f3b[t] * s + bn3b[t] - bn3m[t] * s;
        }
        b3o[t] = v;
    }
    if (t < 16) w4o[t] = (t < 9) ? (f4w[9 + t] - f4w[t]) : 0.f;
    if (t == 0) b4o[0] = f4b[1] - f4b[0];
}

__global__ __launch_bounds__(NTHR, 3) void recovery_net_kernel(
    const float* __restrict__ xcon, const int* __restrict__ xcat,
    const char* __restrict__ ws, float2* __restrict__ out)
{
    __shared__ ushort s_x[16384];    // [256 rows][64 k] f16, XOR-swizzled (32 KB)
    __shared__ uint  s_catp[1856];   // packed byte categories [256][29]
    __shared__ float s_xcon[1792];   // [256][7]
    __shared__ float s_tab[928];     // 4 replicated copies of [29][8]

    const int t = threadIdx.x;
    const int lane = t & 63, w = t >> 6;
    const int l15 = lane & 15, g = lane >> 4;
    char* xb = (char*)s_x;

    // ---- stage (coalesced) ----
    {
        const int4* src = (const int4*)(xcat + (size_t)blockIdx.x * 7424);
        for (int i = t; i < 1856; i += NTHR) {
            int4 v = src[i];
            s_catp[i] = (uint)(v.x & 0xff) | ((uint)(v.y & 0xff) << 8) |
                        ((uint)(v.z & 0xff) << 16) | ((uint)(v.w & 0xff) << 24);
        }
        const float4* s2 = (const float4*)(xcon + (size_t)blockIdx.x * 1792);
        for (int i = t; i < 448; i += NTHR) ((float4*)s_xcon)[i] = s2[i];
        const float* tws = (const float*)(ws + TAB_B);
        for (int cp = 0; cp < 4; cp++)
            for (int i = t; i < 232; i += NTHR) s_tab[cp * 232 + i] = tws[i];
    }
    __syncthreads();
    // ---- everything below is wave-local (wave w owns rows 64w..64w+63) ----

    // X fill: thread t builds row t = [xcon(7) | tab(29) | 0...]
    {
        const unsigned char* myc = ((const unsigned char*)s_catp) + t * 29;
        const float* tb = s_tab + ((t >> 4) & 3) * 232;
        float v[64];
#pragma unroll
        for (int k = 0; k < 7; k++) v[k] = s_xcon[t * 7 + k];
#pragma unroll
        for (int j = 0; j < 29; j++) v[7 + j] = tb[j * 8 + (int)myc[j]];
#pragma unroll
        for (int k = 36; k < 64; k++) v[k] = 0.f;
        const int rbase = t * 128, sw = (t & 7) << 4;
#pragma unroll
        for (int j = 0; j < 8; j++) {
            uint p0 = pk2(v[8 * j + 0], v[8 * j + 1]);
            uint p1 = pk2(v[8 * j + 2], v[8 * j + 3]);
            uint p2 = pk2(v[8 * j + 4], v[8 * j + 5]);
            uint p3 = pk2(v[8 * j + 6], v[8 * j + 7]);
            *(uint4*)(xb + ((rbase + j * 16) ^ sw)) = make_uint4(p0, p1, p2, p3);
        }
    }

    const int rb = w * 64;  // this wave's row strip
    const ushort* w1p = (const ushort*)(ws + W1_B);
    const ushort* w2p = (const ushort*)(ws + W2_B);
    const ushort* w3p = (const ushort*)(ws + W3_B);
    const float* b1p = (const float*)(ws + B1_B);
    const float* b2p = (const float*)(ws + B2_B);
    const float* b3p = (const float*)(ws + B3_B);
    const float* w4p = (const float*)(ws + W4_B);
    const float* b4p = (const float*)(ws + B4_B);

    // ---- fc1: [64 rows x 64k] @ W1^T -> h1 [64 x 48] ----
    {
        f16x8 bf[3][2];
#pragma unroll
        for (int nt = 0; nt < 3; nt++) {
            bf[nt][0] = ldb_frag(w1p, nt * 16 + l15, 64, 0, g);
            bf[nt][1] = ldb_frag(w1p, nt * 16 + l15, 64, 32, g);
        }
        f32x4 acc[4][3];
#pragma unroll
        for (int nt = 0; nt < 3; nt++) {
            float bv = b1p[nt * 16 + l15];
#pragma unroll
            for (int mt = 0; mt < 4; mt++) acc[mt][nt] = f32x4{bv, bv, bv, bv};
        }
#pragma unroll
        for (int mt = 0; mt < 4; mt++) {
            f16x8 a0 = lda_frag(xb, rb + mt * 16 + l15, 0, g);
            f16x8 a1 = lda_frag(xb, rb + mt * 16 + l15, 32, g);
#pragma unroll
            for (int nt = 0; nt < 3; nt++) {
                acc[mt][nt] = __builtin_amdgcn_mfma_f32_16x16x32_f16(a0, bf[nt][0], acc[mt][nt], 0, 0, 0);
                acc[mt][nt] = __builtin_amdgcn_mfma_f32_16x16x32_f16(a1, bf[nt][1], acc[mt][nt], 0, 0, 0);
            }
        }
        // relu + write h1 back into cols 0..47 (cols 48-63 stay zero)
#pragma unroll
        for (int mt = 0; mt < 4; mt++)
#pragma unroll
            for (int nt = 0; nt < 3; nt++)
#pragma unroll
                for (int r = 0; r < 4; r++) {
                    int row = rb + mt * 16 + 4 * g + r;
                    int col = nt * 16 + l15;
                    int b = (row * 128 + col * 2) ^ ((row & 7) << 4);
                    *(ushort*)(xb + b) = f16bits(fmaxf(acc[mt][nt][r], 0.f));
                }
    }

    // ---- fc2: h1 [64 x 64k] @ W2^T -> h2 [64 x 32] ----
    {
        f16x8 bf[2][2];
#pragma unroll
        for (int nt = 0; nt < 2; nt++) {
            bf[nt][0] = ldb_frag(w2p, nt * 16 + l15, 64, 0, g);
            bf[nt][1] = ldb_frag(w2p, nt * 16 + l15, 64, 32, g);
        }
        f32x4 acc[4][2];
#pragma unroll
        for (int nt = 0; nt < 2; nt++) {
            float bv = b2p[nt * 16 + l15];
#pragma unroll
            for (int mt = 0; mt < 4; mt++) acc[mt][nt] = f32x4{bv, bv, bv, bv};
        }
#pragma unroll
        for (int mt = 0; mt < 4; mt++) {
            f16x8 a0 = lda_frag(xb, rb + mt * 16 + l15, 0, g);
            f16x8 a1 = lda_frag(xb, rb + mt * 16 + l15, 32, g);
#pragma unroll
            for (int nt = 0; nt < 2; nt++) {
                acc[mt][nt] = __builtin_amdgcn_mfma_f32_16x16x32_f16(a0, bf[nt][0], acc[mt][nt], 0, 0, 0);
                acc[mt][nt] = __builtin_amdgcn_mfma_f32_16x16x32_f16(a1, bf[nt][1], acc[mt][nt], 0, 0, 0);
            }
        }
#pragma unroll
        for (int mt = 0; mt < 4; mt++)
#pragma unroll
            for (int nt = 0; nt < 2; nt++)
#pragma unroll
                for (int r = 0; r < 4; r++) {
                    int row = rb + mt * 16 + 4 * g + r;
                    int col = nt * 16 + l15;
                    int b = (row * 128 + col * 2) ^ ((row & 7) << 4);
                    *(ushort*)(xb + b) = f16bits(fmaxf(acc[mt][nt][r], 0.f));
                }
    }

    // ---- fc3 (K=32) + fc4 delta reduce + sigmoid ----
    {
        f16x8 bf = ldb_frag(w3p, l15, 32, 0, g);
        float bv = b3p[l15];
        float w4v = w4p[l15];
        float b4v = *b4p;
        f32x4 acc[4];
#pragma unroll
        for (int mt = 0; mt < 4; mt++) acc[mt] = f32x4{bv, bv, bv, bv};
#pragma unroll
        for (int mt = 0; mt < 4; mt++) {
            f16x8 a0 = lda_frag(xb, rb + mt * 16 + l15, 0, g);
            acc[mt] = __builtin_amdgcn_mfma_f32_16x16x32_f16(a0, bf, acc[mt], 0, 0, 0);
        }
#pragma unroll
        for (int mt = 0; mt < 4; mt++) {
            float dr[4];
#pragma unroll
            for (int r = 0; r < 4; r++) {
                float x = fmaxf(acc[mt][r], 0.f) * w4v;
                x += __shfl_xor(x, 1);
                x += __shfl_xor(x, 2);
                x += __shfl_xor(x, 4);
                x += __shfl_xor(x, 8);
                dr[r] = x;
            }
            float d = (l15 == 0) ? dr[0] : (l15 == 1) ? dr[1] : (l15 == 2) ? dr[2] : dr[3];
            d += b4v;
            float p1 = 1.f / (1.f + __expf(-d));
            if (l15 < 4) {
                int row = blockIdx.x * 256 + rb + mt * 16 + 4 * g + l15;
                out[row] = make_float2(1.f - p1, p1);
            }
        }
    }
}

extern "C" void kernel_launch(void* const* d_in, const int* in_sizes, int n_in,
                              void* d_out, int out_size, void* d_ws, size_t ws_size,
                              hipStream_t stream) {
    (void)in_sizes; (void)n_in; (void)ws_size; (void)out_size;
    char* ws = (char*)d_ws;
    prep_kernel<<<1, NTHR, 0, stream>>>(
        (const float*)d_in[2],  (const float*)d_in[3],
        (const float*)d_in[4],  (const float*)d_in[5],
        (const float*)d_in[6],
        (const float*)d_in[7],  (const float*)d_in[8],
        (const float*)d_in[9],  (const float*)d_in[10],
        (const float*)d_in[11], (const float*)d_in[12],
        (const float*)d_in[13], (const float*)d_in[14],
        (const float*)d_in[15], (const float*)d_in[16],
        (const float*)d_in[17], (const float*)d_in[18],
        (const float*)d_in[19], (const float*)d_in[20],
        (const float*)d_in[21], (const float*)d_in[22],
        (const float*)d_in[23], (const float*)d_in[24],
        (const float*)d_in[25], (const float*)d_in[26],
        (const float*)d_in[27], (const float*)d_in[28],
        (const float*)d_in[29], (const float*)d_in[30],
        ws);
    recovery_net_kernel<<<NBLOCKS, NTHR, 0, stream>>>(
        (const float*)d_in[0], (const int*)d_in[1], ws, (float2*)d_out);
}

// Round 5
// 77.917 us; speedup vs baseline: 2.4258x; 1.0835x over previous
//
#include <hip/hip_runtime.h>

typedef _Float16 f16x8 __attribute__((ext_vector_type(8)));
typedef __fp16 fp16x2 __attribute__((ext_vector_type(2)));
typedef float f32x4 __attribute__((ext_vector_type(4)));

#define NTHR 256
constexpr float EPS = 1e-5f;
constexpr int NBLOCKS = 4096;   // 1048576 / 256 rows per block

// ---- ws byte offsets (written by prep_kernel every call) ----
#define TAB_B   0       // f32 [29*8]  embedding-MLP table, stride 8
#define W1_B    1024    // f16 [48][64]  fc1 (bn1+cbn folded), out-major, k padded
#define W2_B    7168    // f16 [32][64]  fc2 (bn2 folded)
#define W3_B    11264   // f16 [16][32]  fc3 (bn3 folded)
#define B1_B    12288   // f32 [48]
#define B2_B    12544   // f32 [32]
#define B3_B    12672   // f32 [16]
#define W4_B    12736   // f32 [16]  (fc4 row1-row0, padded)
#define B4_B    12800   // f32 [1]

__device__ __forceinline__ ushort f16bits(float x) {
    union { _Float16 h; ushort u; } c; c.h = (_Float16)x; return c.u;
}
__device__ __forceinline__ uint pk2(float a, float b) {
    union { fp16x2 h; uint u; } c; c.h = __builtin_amdgcn_cvt_pkrtz(a, b); return c.u;
}
__device__ __forceinline__ uint pkrelu(float a, float b) {
    return pk2(fmaxf(a, 0.f), fmaxf(b, 0.f));
}
__device__ __forceinline__ f16x8 mk8(uint a, uint b, uint c, uint d) {
    union { uint u[4]; f16x8 v; } f;
    f.u[0] = a; f.u[1] = b; f.u[2] = c; f.u[3] = d;
    return f.v;
}

// Weight A-fragment from global [n][stride] f16: lane m=l&15, k = kb+4g.., kb+16+4g..
__device__ __forceinline__ f16x8 ldw_frag(const ushort* wp, int m, int stride, int kb, int g) {
    const ushort* p = wp + m * stride + kb + 4 * g;
    uint2 lo = *(const uint2*)p;
    uint2 hi = *(const uint2*)(p + 16);
    return mk8(lo.x, lo.y, hi.x, hi.y);
}

__global__ __launch_bounds__(NTHR) void prep_kernel(
    const float* __restrict__ embt, const float* __restrict__ w1,
    const float* __restrict__ b1,   const float* __restrict__ w2,
    const float* __restrict__ b2,
    const float* __restrict__ cbn_g, const float* __restrict__ cbn_b,
    const float* __restrict__ cbn_m, const float* __restrict__ cbn_v,
    const float* __restrict__ f1w, const float* __restrict__ f1b,
    const float* __restrict__ f2w, const float* __restrict__ f2b,
    const float* __restrict__ f3w, const float* __restrict__ f3b,
    const float* __restrict__ f4w, const float* __restrict__ f4b,
    const float* __restrict__ bn1g, const float* __restrict__ bn1b,
    const float* __restrict__ bn1m, const float* __restrict__ bn1v,
    const float* __restrict__ bn2g, const float* __restrict__ bn2b,
    const float* __restrict__ bn2m, const float* __restrict__ bn2v,
    const float* __restrict__ bn3g, const float* __restrict__ bn3b,
    const float* __restrict__ bn3m, const float* __restrict__ bn3v,
    char* __restrict__ ws)
{
    const int t = threadIdx.x;
    float* tab = (float*)(ws + TAB_B);
    ushort* w1o = (ushort*)(ws + W1_B);
    ushort* w2o = (ushort*)(ws + W2_B);
    ushort* w3o = (ushort*)(ws + W3_B);
    float* b1o = (float*)(ws + B1_B);
    float* b2o = (float*)(ws + B2_B);
    float* b3o = (float*)(ws + B3_B);
    float* w4o = (float*)(ws + W4_B);
    float* b4o = (float*)(ws + B4_B);

    // embedding-MLP lookup table [29][8] (stride 8, cols 5-7 zero)
    for (int i = t; i < 232; i += NTHR) {
        int j = i / 8, c = i % 8;
        float xe = 0.f;
        if (c < 5) {
            xe = b2[j];
            for (int e = 0; e < 6; e++) {
                float a = b1[j * 6 + e];
                for (int d = 0; d < 6; d++)
                    a += embt[(j * 5 + c) * 6 + d] * w1[j * 36 + d * 6 + e];
                xe += fmaxf(a, 0.f) * w2[j * 6 + e];
            }
        }
        tab[i] = xe;
    }
    // fc1: [48 out][64 k] f16, bn1 scale on rows, cbn scale on cols<7, pads zero
    for (int i = t; i < 3072; i += NTHR) {
        int n = i / 64, k = i % 64;
        float v = 0.f;
        if (n < 36 && k < 36) {
            float s1 = bn1g[n] * rsqrtf(bn1v[n] + EPS);
            v = f1w[n * 36 + k] * s1;
            if (k < 7) v *= cbn_g[k] * rsqrtf(cbn_v[k] + EPS);
        }
        w1o[i] = f16bits(v);
    }
    if (t < 48) {
        float v = 0.f;
        if (t < 36) {
            float s1 = bn1g[t] * rsqrtf(bn1v[t] + EPS);
            v = f1b[t] * s1 + bn1b[t] - bn1m[t] * s1;
            for (int k = 0; k < 7; k++) {
                float cs = cbn_g[k] * rsqrtf(cbn_v[k] + EPS);
                float ct = cbn_b[k] - cbn_m[k] * cs;
                v += f1w[t * 36 + k] * s1 * ct;
            }
        }
        b1o[t] = v;
    }
    // fc2: [32 out][64 k]
    for (int i = t; i < 2048; i += NTHR) {
        int n = i / 64, k = i % 64;
        float v = 0.f;
        if (n < 18 && k < 36) {
            float s = bn2g[n] * rsqrtf(bn2v[n] + EPS);
            v = f2w[n * 36 + k] * s;
        }
        w2o[i] = f16bits(v);
    }
    if (t < 32) {
        float v = 0.f;
        if (t < 18) {
            float s = bn2g[t] * rsqrtf(bn2v[t] + EPS);
            v = f2b[t] * s + bn2b[t] - bn2m[t] * s;
        }
        b2o[t] = v;
    }
    // fc3: [16 out][32 k]
    for (int i = t; i < 512; i += NTHR) {
        int n = i / 32, k = i % 32;
        float v = 0.f;
        if (n < 9 && k < 18) {
            float s = bn3g[n] * rsqrtf(bn3v[n] + EPS);
            v = f3w[n * 18 + k] * s;
        }
        w3o[i] = f16bits(v);
    }
    if (t < 16) {
        float v = 0.f;
        if (t < 9) {
            float s = bn3g[t] * rsqrtf(bn3v[t] + EPS);
            v = f3b[t] * s + bn3b[t] - bn3m[t] * s;
        }
        b3o[t] = v;
    }
    if (t < 16) w4o[t] = (t < 9) ? (f4w[9 + t] - f4w[t]) : 0.f;
    if (t == 0) b4o[0] = f4b[1] - f4b[0];
}

// X LDS layout: [256 rows][44 f16] (88 B row stride; words 0..17 = features 0..35)
#define XSTRIDE 88

__global__ __launch_bounds__(NTHR, 4) void recovery_net_kernel(
    const float* __restrict__ xcon, const int* __restrict__ xcat,
    const char* __restrict__ ws, float2* __restrict__ out)
{
    __shared__ __align__(16) char s_x[256 * XSTRIDE];   // 22528 B
    __shared__ uint  s_catp[1856];   // packed byte categories [256][29]
    __shared__ float s_xcon[1792];   // [256][7]
    __shared__ float s_tab[464];     // 2 replicated copies of [29][8]

    const int t = threadIdx.x;
    const int lane = t & 63, w = t >> 6;
    const int l15 = lane & 15, g = lane >> 4;

    // ---- stage inputs (coalesced) ----
    {
        const int4* src = (const int4*)(xcat + (size_t)blockIdx.x * 7424);
        for (int i = t; i < 1856; i += NTHR) {
            int4 v = src[i];
            s_catp[i] = (uint)(v.x & 0xff) | ((uint)(v.y & 0xff) << 8) |
                        ((uint)(v.z & 0xff) << 16) | ((uint)(v.w & 0xff) << 24);
        }
        const float4* s2 = (const float4*)(xcon + (size_t)blockIdx.x * 1792);
        for (int i = t; i < 448; i += NTHR) ((float4*)s_xcon)[i] = s2[i];
        const float* tws = (const float*)(ws + TAB_B);
        for (int i = t; i < 464; i += NTHR) s_tab[i] = tws[i % 232];
    }
    __syncthreads();
    // ---- everything below is wave-local (wave w owns s_x rows 64w..64w+63) ----

    // X fill: thread t builds row t = [xcon(7) | tab(29)], packed f16
    {
        const unsigned char* myc = ((const unsigned char*)s_catp) + t * 29;
        const float* tb = s_tab + ((t >> 5) & 1) * 232;
        float v[36];
#pragma unroll
        for (int k = 0; k < 7; k++) v[k] = s_xcon[t * 7 + k];
#pragma unroll
        for (int j = 0; j < 29; j++) v[7 + j] = tb[j * 8 + (int)myc[j]];
        uint wd[18];
#pragma unroll
        for (int j = 0; j < 18; j++) wd[j] = pk2(v[2 * j], v[2 * j + 1]);
        char* xb = s_x + t * XSTRIDE;
#pragma unroll
        for (int j = 0; j < 9; j++)
            *(uint2*)(xb + 8 * j) = make_uint2(wd[2 * j], wd[2 * j + 1]);
    }

    const int rb = w * 64;  // this wave's row strip
    const ushort* w1p = (const ushort*)(ws + W1_B);
    const ushort* w2p = (const ushort*)(ws + W2_B);
    const ushort* w3p = (const ushort*)(ws + W3_B);
    const float* b1p = (const float*)(ws + B1_B);
    const float* b2p = (const float*)(ws + B2_B);
    const float* b3p = (const float*)(ws + B3_B);
    const float* w4p = (const float*)(ws + W4_B);
    const float* b4p = (const float*)(ws + B4_B);

    // ---- weight A-fragments (features = m), held across tiles ----
    f16x8 a1[3][2], a2[2][2], a3;
#pragma unroll
    for (int mt = 0; mt < 3; mt++) {
        a1[mt][0] = ldw_frag(w1p, mt * 16 + l15, 64, 0, g);
        a1[mt][1] = ldw_frag(w1p, mt * 16 + l15, 64, 32, g);
    }
#pragma unroll
    for (int mt = 0; mt < 2; mt++) {
        a2[mt][0] = ldw_frag(w2p, mt * 16 + l15, 64, 0, g);
        a2[mt][1] = ldw_frag(w2p, mt * 16 + l15, 64, 32, g);
    }
    a3 = ldw_frag(w3p, l15, 32, 0, g);

    // biases / fc4 (per-lane float4 at row m = mt*16 + 4g + r)
    const float4 b1v0 = *(const float4*)(b1p + 4 * g);
    const float4 b1v1 = *(const float4*)(b1p + 16 + 4 * g);
    const float4 b1v2 = *(const float4*)(b1p + 32 + 4 * g);
    const float4 b2v0 = *(const float4*)(b2p + 4 * g);
    const float4 b2v1 = *(const float4*)(b2p + 16 + 4 * g);
    const float4 b3v  = *(const float4*)(b3p + 4 * g);
    const float4 w4v  = *(const float4*)(w4p + 4 * g);
    const float b4s = *b4p;

    // ---- 4 batch tiles of 16 rows; whole chain in registers ----
#pragma unroll
    for (int bt = 0; bt < 4; bt++) {
        const char* xr = s_x + (rb + 16 * bt + l15) * XSTRIDE;
        uint2 q0 = *(const uint2*)(xr + 8 * g);        // features 4g..4g+3
        uint2 q1 = *(const uint2*)(xr + 32 + 8 * g);   // features 16+4g..19+4g
        uint2 q2 = *(const uint2*)(xr + 64);           // features 32..35
        f16x8 xb0 = mk8(q0.x, q0.y, q1.x, q1.y);
        f16x8 xb1 = mk8(g == 0 ? q2.x : 0u, g == 0 ? q2.y : 0u, 0u, 0u);

        // fc1: h1^T tiles (features 0..47)
        f32x4 c10 = f32x4{b1v0.x, b1v0.y, b1v0.z, b1v0.w};
        f32x4 c11 = f32x4{b1v1.x, b1v1.y, b1v1.z, b1v1.w};
        f32x4 c12 = f32x4{b1v2.x, b1v2.y, b1v2.z, b1v2.w};
        c10 = __builtin_amdgcn_mfma_f32_16x16x32_f16(a1[0][0], xb0, c10, 0, 0, 0);
        c11 = __builtin_amdgcn_mfma_f32_16x16x32_f16(a1[1][0], xb0, c11, 0, 0, 0);
        c12 = __builtin_amdgcn_mfma_f32_16x16x32_f16(a1[2][0], xb0, c12, 0, 0, 0);
        c10 = __builtin_amdgcn_mfma_f32_16x16x32_f16(a1[0][1], xb1, c10, 0, 0, 0);
        c11 = __builtin_amdgcn_mfma_f32_16x16x32_f16(a1[1][1], xb1, c11, 0, 0, 0);
        c12 = __builtin_amdgcn_mfma_f32_16x16x32_f16(a1[2][1], xb1, c12, 0, 0, 0);

        // relu + pack: C1 tiles are exactly fc2's B-fragments
        f16x8 h0 = mk8(pkrelu(c10.x, c10.y), pkrelu(c10.z, c10.w),
                       pkrelu(c11.x, c11.y), pkrelu(c11.z, c11.w));
        f16x8 h1 = mk8(pkrelu(c12.x, c12.y), pkrelu(c12.z, c12.w), 0u, 0u);

        // fc2
        f32x4 c20 = f32x4{b2v0.x, b2v0.y, b2v0.z, b2v0.w};
        f32x4 c21 = f32x4{b2v1.x, b2v1.y, b2v1.z, b2v1.w};
        c20 = __builtin_amdgcn_mfma_f32_16x16x32_f16(a2[0][0], h0, c20, 0, 0, 0);
        c21 = __builtin_amdgcn_mfma_f32_16x16x32_f16(a2[1][0], h0, c21, 0, 0, 0);
        c20 = __builtin_amdgcn_mfma_f32_16x16x32_f16(a2[0][1], h1, c20, 0, 0, 0);
        c21 = __builtin_amdgcn_mfma_f32_16x16x32_f16(a2[1][1], h1, c21, 0, 0, 0);

        // fc3
        f16x8 h2 = mk8(pkrelu(c20.x, c20.y), pkrelu(c20.z, c20.w),
                       pkrelu(c21.x, c21.y), pkrelu(c21.z, c21.w));
        f32x4 c3 = f32x4{b3v.x, b3v.y, b3v.z, b3v.w};
        c3 = __builtin_amdgcn_mfma_f32_16x16x32_f16(a3, h2, c3, 0, 0, 0);

        // fc4 delta + sigmoid: reduce feature partials across g-groups
        float part = fmaxf(c3.x, 0.f) * w4v.x + fmaxf(c3.y, 0.f) * w4v.y +
                     fmaxf(c3.z, 0.f) * w4v.z + fmaxf(c3.w, 0.f) * w4v.w;
        part += __shfl_xor(part, 16);
        part += __shfl_xor(part, 32);
        float d = part + b4s;
        float p1 = 1.f / (1.f + __expf(-d));
        if (g == 0)
            out[blockIdx.x * 256 + rb + 16 * bt + l15] = make_float2(1.f - p1, p1);
    }
}

extern "C" void kernel_launch(void* const* d_in, const int* in_sizes, int n_in,
                              void* d_out, int out_size, void* d_ws, size_t ws_size,
                              hipStream_t stream) {
    (void)in_sizes; (void)n_in; (void)ws_size; (void)out_size;
    char* ws = (char*)d_ws;
    prep_kernel<<<1, NTHR, 0, stream>>>(
        (const float*)d_in[2],  (const float*)d_in[3],
        (const float*)d_in[4],  (const float*)d_in[5],
        (const float*)d_in[6],
        (const float*)d_in[7],  (const float*)d_in[8],
        (const float*)d_in[9],  (const float*)d_in[10],
        (const float*)d_in[11], (const float*)d_in[12],
        (const float*)d_in[13], (const float*)d_in[14],
        (const float*)d_in[15], (const float*)d_in[16],
        (const float*)d_in[17], (const float*)d_in[18],
        (const float*)d_in[19], (const float*)d_in[20],
        (const float*)d_in[21], (const float*)d_in[22],
        (const float*)d_in[23], (const float*)d_in[24],
        (const float*)d_in[25], (const float*)d_in[26],
        (const float*)d_in[27], (const float*)d_in[28],
        (const float*)d_in[29], (const float*)d_in[30],
        ws);
    recovery_net_kernel<<<NBLOCKS, NTHR, 0, stream>>>(
        (const float*)d_in[0], (const int*)d_in[1], ws, (float2*)d_out);
}